// Round 9
// baseline (162.689 us; speedup 1.0000x reference)
//
#include <hip/hip_runtime.h>
#include <stdint.h>

// ---------------------------------------------------------------------------
// SlidingWindowAttention: B=2, N=2048, C=1024, H=16, Dh=64, window=512 (half=256)
// fp16 MFMA pipeline (4 dispatches):
//   prep: x->fp16, W_qkv^T, W_proj^T
//   GEMM1 128x128 BK=64 (2-barrier), 32x32x16 MFMA: QKV = Xb @ Wqt^T
//     -> Q(prescaled 0.125*log2e)/K planes; V section -> Vt [bh][dh][2048] b64
//   attn v3 (R6): 32x32 MFMA, 128q x 8 waves, K/V dbuf, LDS-P 72B pitch
//   GEMM2 128x64 BK=64, 32x32x16 MFMA: out = O2 @ Wpt^T + bias (fp32)
// Lessons: R7 — 1-barrier dbuf pays full DMA latency per iter (syncthreads
// drains vmcnt(0) incl fresh prefetch); R9 — 32x32x16 = 17% less MFMA pipe
// time at identical LDS traffic/occupancy (m119).
// Fixed floor: ~46us/iter harness poison fills.
// ---------------------------------------------------------------------------

typedef _Float16 f16x8 __attribute__((ext_vector_type(8)));
typedef _Float16 f16x4 __attribute__((ext_vector_type(4)));
typedef __fp16   fp16x2n __attribute__((ext_vector_type(2)));
typedef float    f32x2 __attribute__((ext_vector_type(2)));
typedef float    f32x4 __attribute__((ext_vector_type(4)));
typedef float    f32x16 __attribute__((ext_vector_type(16)));

#define MFMA32(a, b, c) __builtin_amdgcn_mfma_f32_32x32x16_f16((a), (b), (c), 0, 0, 0)

__device__ __forceinline__ void gload16(const void* g, void* l) {
  __builtin_amdgcn_global_load_lds(
      (const __attribute__((address_space(1))) void*)g,
      (__attribute__((address_space(3))) void*)l, 16, 0, 0);
}

__device__ __forceinline__ unsigned pk2(float a, float b) {
  fp16x2n t = __builtin_amdgcn_cvt_pkrtz(a, b);
  return __builtin_bit_cast(unsigned, t);
}

// -------------------------- fused prep -------------------------------------
__global__ __launch_bounds__(256) void prep(const float* __restrict__ x,
                                            const float* __restrict__ wqkv,
                                            const float* __restrict__ wproj,
                                            _Float16* __restrict__ Xb,
                                            _Float16* __restrict__ Wqt,
                                            _Float16* __restrict__ Wpt) {
  __shared__ float t[64][65];
  const int id = blockIdx.x, tid = threadIdx.x;
  if (id < 4096) {
    int i = (id * 256 + tid) * 4;
    float4 v = *(const float4*)(x + i);
    f16x4 h;
    h[0] = (_Float16)v.x; h[1] = (_Float16)v.y;
    h[2] = (_Float16)v.z; h[3] = (_Float16)v.w;
    *(f16x4*)(Xb + i) = h;
    return;
  }
  const float* in; _Float16* out; int N, bx, by;
  if (id < 4864) { int tt = id - 4096; in = wqkv; out = Wqt; N = 3072; bx = tt % 48; by = tt / 48; }
  else           { int tt = id - 4864; in = wproj; out = Wpt; N = 1024; bx = tt & 15; by = tt >> 4; }
  const int n0 = bx * 64, k0 = by * 64;
  {
    int j = tid & 63;
#pragma unroll
    for (int p = 0; p < 16; p++) {
      int i = p * 4 + (tid >> 6);
      t[i][j] = in[(size_t)(k0 + i) * N + n0 + j];
    }
  }
  __syncthreads();
  {
    int i = tid & 63;
#pragma unroll
    for (int p = 0; p < 16; p++) {
      int j = p * 4 + (tid >> 6);
      out[(size_t)(n0 + j) * 1024 + k0 + i] = (_Float16)t[i][j];
    }
  }
}

// -------------------------- GEMM BK=64, 32x32x16 MFMA ----------------------
// C = A[M][K] @ Bt[N][K]^T, BMxBN tiles, 256 thr = 4 waves (2x2), wave-tile
// (BM/2)x(BN/2) as (RF x CF) 32x32 frags. LDS rows 128B, 8x16B chunks
// XOR-swizzled: slot = chunk ^ (row&7). A/B frag: lane(cl,hl) reads row/col
// base+cl, k = 16ks + 8hl + j (attn-proven pattern).
// C-layout (m74/m101): col = cl, row = (reg&3) + 8*(reg>>2) + 4*hl.
// EPI==0: Q/K planes scalar b16 (Q prescaled); V section -> Vt packed b64.
// EPI==1: fp32 out + bias.
template <int BM, int BN, int EPI>
__global__ __launch_bounds__(256) void gemm16(const _Float16* __restrict__ A,
                                              const _Float16* __restrict__ Bt,
                                              const int K,
                                              _Float16* __restrict__ oh,
                                              _Float16* __restrict__ vt,
                                              float* __restrict__ of,
                                              const float* __restrict__ bias,
                                              const int Nout) {
  constexpr int RF = BM / 64, CF = BN / 64;
  constexpr int SLABS = (BM + BN) / 8;
  __shared__ __align__(16) char smem[(BM + BN) * 128];
  char* As = smem;
  char* Bs = smem + BM * 128;
  const int tid = threadIdx.x, wave = tid >> 6, lane = tid & 63;
  const int cl = lane & 31, hl = lane >> 5;
  const int bm = blockIdx.y * BM, bn = blockIdx.x * BN;
  const int wm = wave >> 1, wn = wave & 1;
  const int rs = lane >> 3, cp = lane & 7;

  f32x16 acc[RF][CF] = {};

  for (int k0 = 0; k0 < K; k0 += 64) {
    __syncthreads();
#pragma unroll
    for (int s0 = 0; s0 < SLABS / 4; s0++) {
      int s = wave + s0 * 4;
      int row = s * 8 + rs;
      int c = cp ^ (row & 7);
      if (row < BM)
        gload16(A + (size_t)(bm + row) * K + k0 + c * 8, As + s * 1024);
      else
        gload16(Bt + (size_t)(bn + row - BM) * K + k0 + c * 8, smem + s * 1024);
    }
    __syncthreads();
#pragma unroll
    for (int ks = 0; ks < 4; ks++) {
      f16x8 af[RF], bf[CF];
#pragma unroll
      for (int rf = 0; rf < RF; rf++) {
        int R = wm * (BM / 2) + rf * 32 + cl;
        af[rf] = *(const f16x8*)(As + R * 128 + (((ks * 2 + hl) ^ (R & 7)) * 16));
      }
#pragma unroll
      for (int cf = 0; cf < CF; cf++) {
        int C = wn * (BN / 2) + cf * 32 + cl;
        bf[cf] = *(const f16x8*)(Bs + C * 128 + (((ks * 2 + hl) ^ (C & 7)) * 16));
      }
#pragma unroll
      for (int rf = 0; rf < RF; rf++)
#pragma unroll
        for (int cf = 0; cf < CF; cf++)
          acc[rf][cf] = MFMA32(af[rf], bf[cf], acc[rf][cf]);
    }
  }

#pragma unroll
  for (int rf = 0; rf < RF; rf++)
#pragma unroll
    for (int cf = 0; cf < CF; cf++) {
      const int rbase = bm + wm * (BM / 2) + rf * 32 + 4 * hl;
      const int col = bn + wn * (BN / 2) + cf * 32 + cl;
      if (EPI == 0) {
        const int sec = col >> 10, cc = col & 1023;
        if (sec == 2) {
          // V -> Vt [b*16+h][dh][2048]: quad g = 4 consecutive n at fixed dh
          const int bh = ((rbase >> 11) << 4) + (cc >> 6), dh = cc & 63;
          _Float16* vdst = vt + (size_t)bh * 131072 + (size_t)dh * 2048;
#pragma unroll
          for (int g = 0; g < 4; g++) {
            int n = (rbase & 2047) + 8 * g;
            uint2 u = {pk2(acc[rf][cf][4 * g + 0], acc[rf][cf][4 * g + 1]),
                       pk2(acc[rf][cf][4 * g + 2], acc[rf][cf][4 * g + 3])};
            *(uint2*)(vdst + n) = u;
          }
        } else {
          const size_t plane = (size_t)(sec * 32 + ((rbase >> 11) << 4) + (cc >> 6));
          _Float16* pdst = oh + plane * 131072 + (cc & 63);
#pragma unroll
          for (int r = 0; r < 16; r++) {
            int row = (rbase & 2047) + (r & 3) + 8 * (r >> 2);
            float v = acc[rf][cf][r];
            if (sec == 0) v *= 0.18033688f;  // fold 0.125*log2(e) into Q
            pdst[(size_t)row * 64] = (_Float16)v;
          }
        }
      } else {
#pragma unroll
        for (int r = 0; r < 16; r++) {
          int row = rbase + (r & 3) + 8 * (r >> 2);
          of[(size_t)row * Nout + col] = acc[rf][cf][r] + bias[col];
        }
      }
    }
}

// -------------------------- banded flash attention v3 (R6, unchanged) ------
__global__ __launch_bounds__(512) void attn(const _Float16* __restrict__ QKV,
                                            const _Float16* __restrict__ VT,
                                            _Float16* __restrict__ O2) {
  __shared__ __align__(16) char smem[51200];
  const int tid = threadIdx.x, wave = tid >> 6, lane = tid & 63;
  const int qw = wave >> 1, sh = wave & 1;
  const int cl = lane & 31, hl = lane >> 5;
  const int rs = lane >> 3, cp = lane & 7;
  const int q0 = blockIdx.x * 128, bh = blockIdx.y;
  const _Float16* Qg = QKV + (size_t)bh * 131072;
  const _Float16* Kg = QKV + 4194304 + (size_t)bh * 131072;
  const _Float16* Vg = VT + (size_t)bh * 131072;
  const int t0 = (q0 >= 256) ? q0 - 256 : 0;
  const int t1 = (q0 + 384 <= 2048) ? q0 + 384 : 2048;
  const int niter = (t1 - t0) >> 6;

#pragma unroll
  for (int q = 0; q < 2; q++) {
    int s = 2 * wave + q;
    int row = s * 8 + rs;
    int c = cp ^ (row & 7);
    gload16(Qg + (size_t)(q0 + row) * 64 + c * 8, smem + s * 1024);
  }
  {
    char* B0 = smem + 18432;
    int row = wave * 8 + rs;
    int c = cp ^ (row & 7);
    gload16(Kg + (size_t)(t0 + row) * 64 + c * 8, B0 + wave * 1024);
    gload16(Vg + (size_t)row * 2048 + t0 + c * 8, B0 + 8192 + wave * 1024);
  }
  __syncthreads();

  f16x8 bq[4];
  {
    int row = 32 * qw + cl;
#pragma unroll
    for (int ks = 0; ks < 4; ks++)
      bq[ks] = *(const f16x8*)(smem + row * 128 + (((ks * 2 + hl) ^ (row & 7)) * 16));
  }
  __syncthreads();  // Q reads done before P overwrites staging region

  char* Pw = smem + wave * 2304;  // 32 rows x 72B
  f32x16 oacc[2] = {};
  float l_acc = 0.f;
  const int a0 = q0 + 32 * qw;

  for (int i = 0; i < niter; i++) {
    const int kt = t0 + i * 64;
    char* Bc = smem + 18432 + (i & 1) * 16384;
    if (i + 1 < niter) {
      char* Bn = smem + 18432 + ((i + 1) & 1) * 16384;
      int row = wave * 8 + rs;
      int c = cp ^ (row & 7);
      gload16(Kg + (size_t)(kt + 64 + row) * 64 + c * 8, Bn + wave * 1024);
      gload16(Vg + (size_t)row * 2048 + (kt + 64) + c * 8, Bn + 8192 + wave * 1024);
    }
    const int d0 = a0 - (kt + 32 * sh);
    if (d0 < 288 && d0 > -288) {
      char* Ksm = Bc;
      char* Vsm = Bc + 8192;
      f32x16 st = {};
      {
        const int krow = 32 * sh + cl;
#pragma unroll
        for (int ks = 0; ks < 4; ks++) {
          f16x8 ak = *(const f16x8*)(Ksm + krow * 128 + (((ks * 2 + hl) ^ (krow & 7)) * 16));
          st = MFMA32(ak, bq[ks], st);
        }
      }
#pragma unroll
      for (int g = 0; g < 4; g++) {
        float v[4];
#pragma unroll
        for (int i2 = 0; i2 < 4; i2++) {
          float e = __builtin_amdgcn_exp2f(st[4 * g + i2]);
          int kl = 8 * g + 4 * hl + i2;
          if (d0 == 256) e = (cl <= kl) ? e : 0.f;
          else if (d0 == -256) e = (cl >= kl) ? e : 0.f;
          l_acc += e;
          v[i2] = e;
        }
        uint2 w2 = {pk2(v[0], v[1]), pk2(v[2], v[3])};
        *(uint2*)(Pw + cl * 72 + 16 * g + 8 * hl) = w2;
      }
#pragma unroll
      for (int ks2 = 0; ks2 < 2; ks2++) {
        union { uint2 u2[2]; f16x8 h; } bp;
        bp.u2[0] = *(const uint2*)(Pw + cl * 72 + 32 * ks2 + 16 * hl);
        bp.u2[1] = *(const uint2*)(Pw + cl * 72 + 32 * ks2 + 16 * hl + 8);
#pragma unroll
        for (int db = 0; db < 2; db++) {
          int vrow = 32 * db + cl;
          f16x8 av = *(const f16x8*)(Vsm + vrow * 128 +
                                     (((4 * sh + 2 * ks2 + hl) ^ (vrow & 7)) * 16));
          oacc[db] = MFMA32(av, bp.h, oacc[db]);
        }
      }
    }
    __syncthreads();
  }

  const float lp = l_acc + __shfl_xor(l_acc, 32);
  char* Mq = smem + qw * 8448;
  if (sh == 1) {
#pragma unroll
    for (int db = 0; db < 2; db++)
#pragma unroll
      for (int g = 0; g < 4; g++) {
        int dh0 = 32 * db + 8 * g + 4 * hl;
        f32x2 a = {oacc[db][4 * g + 0], oacc[db][4 * g + 1]};
        f32x2 b = {oacc[db][4 * g + 2], oacc[db][4 * g + 3]};
        *(f32x2*)(Mq + cl * 264 + dh0 * 4) = a;
        *(f32x2*)(Mq + cl * 264 + dh0 * 4 + 8) = b;
      }
    if (hl == 0) *(float*)(smem + 34816 + (qw * 32 + cl) * 4) = lp;
  }
  __syncthreads();
  if (sh == 0) {
    float lo = *(const float*)(smem + 34816 + (qw * 32 + cl) * 4);
    float inv = 1.0f / (lp + lo);
    const int b = bh >> 4, h = bh & 15;
    _Float16* dst = O2 + (size_t)(b * 2048 + a0 + cl) * 1024 + h * 64;
#pragma unroll
    for (int db = 0; db < 2; db++)
#pragma unroll
      for (int g = 0; g < 4; g++) {
        int dh0 = 32 * db + 8 * g + 4 * hl;
        f32x2 a = *(const f32x2*)(Mq + cl * 264 + dh0 * 4);
        f32x2 b2 = *(const f32x2*)(Mq + cl * 264 + dh0 * 4 + 8);
        uint2 pkd = {pk2((oacc[db][4 * g + 0] + a[0]) * inv,
                         (oacc[db][4 * g + 1] + a[1]) * inv),
                     pk2((oacc[db][4 * g + 2] + b2[0]) * inv,
                         (oacc[db][4 * g + 3] + b2[1]) * inv)};
        *(uint2*)(dst + dh0) = pkd;
      }
  }
}

// -------------------------- host launch ------------------------------------

extern "C" void kernel_launch(void* const* d_in, const int* in_sizes, int n_in,
                              void* d_out, int out_size, void* d_ws, size_t ws_size,
                              hipStream_t stream) {
  const float* x = (const float*)d_in[0];
  const float* wqkv = (const float*)d_in[1];
  const float* wproj = (const float*)d_in[2];
  const float* bproj = (const float*)d_in[3];
  float* out = (float*)d_out;
  char* ws = (char*)d_ws;

  _Float16* Xb  = (_Float16*)(ws);                       // 8 MB [4096][1024]
  _Float16* Wqt = (_Float16*)(ws + (size_t)(8  << 20));  // 6 MB [3072][1024]
  _Float16* Wpt = (_Float16*)(ws + (size_t)(14 << 20));  // 2 MB [1024][1024]
  _Float16* QKV = (_Float16*)(ws + (size_t)(16 << 20));  // 16 MB Q,K planes
  _Float16* Vt  = (_Float16*)(ws + (size_t)(40 << 20));  // 8 MB [32][64][2048]
  _Float16* O2  = (_Float16*)(ws);                       // aliases Xb

  prep<<<5120, 256, 0, stream>>>(x, wqkv, wproj, Xb, Wqt, Wpt);
  gemm16<128, 128, 0><<<dim3(24, 32), 256, 0, stream>>>(Xb, Wqt, 1024, QKV, Vt,
                                                        nullptr, nullptr, 0);
  attn<<<dim3(16, 32), 512, 0, stream>>>(QKV, Vt, O2);
  gemm16<128, 64, 1><<<dim3(16, 32), 256, 0, stream>>>(O2, Wpt, 1024, nullptr,
                                                       nullptr, out, bproj, 1024);
}

// Round 10
// 155.142 us; speedup vs baseline: 1.0486x; 1.0486x over previous
//
#include <hip/hip_runtime.h>
#include <stdint.h>

// ---------------------------------------------------------------------------
// SlidingWindowAttention: B=2, N=2048, C=1024, H=16, Dh=64, window=512 (half=256)
// fp16 MFMA pipeline (4 dispatches) — R8 configuration (best measured: 160.3us):
//   prep: x->fp16, W_qkv^T, W_proj^T
//   GEMM1 128x128 BK=64 (2-barrier, 16x16x32 MFMA): QKV = Xb @ Wqt^T
//     -> Q(prescaled 0.125*log2e)/K planes; V section written DIRECTLY to
//        Vt [bh][dh][2048] as packed b64 (4 consecutive n per C-quad)
//   attn v3 (R6): 32x32 MFMA, 128q x 8 waves, K/V dbuf, LDS-P 72B pitch
//   GEMM2 128x64 BK=64: out = O2 @ Wpt^T + bias (fp32)
// Negative results (do NOT retry): R7 1-barrier dbuf BK=32 (+4.6us —
// __syncthreads drains vmcnt(0) incl fresh prefetch, pays full DMA latency
// per iter); R9 32x32x16 GEMM MFMA (+2.4us — MFMA pipe not critical path,
// worse epilogue scatter); R5 256q attn tiles (+8us — occupancy loss).
// Plateau: ~51us harness poison/restore floor + ~100us kernels at
// m97-structure shape-plateau rates.
// ---------------------------------------------------------------------------

typedef _Float16 f16x8 __attribute__((ext_vector_type(8)));
typedef _Float16 f16x4 __attribute__((ext_vector_type(4)));
typedef __fp16   fp16x2n __attribute__((ext_vector_type(2)));
typedef float    f32x2 __attribute__((ext_vector_type(2)));
typedef float    f32x4 __attribute__((ext_vector_type(4)));
typedef float    f32x16 __attribute__((ext_vector_type(16)));

#define MFMA16(a, b, c) __builtin_amdgcn_mfma_f32_16x16x32_f16((a), (b), (c), 0, 0, 0)
#define MFMA32(a, b, c) __builtin_amdgcn_mfma_f32_32x32x16_f16((a), (b), (c), 0, 0, 0)

__device__ __forceinline__ void gload16(const void* g, void* l) {
  __builtin_amdgcn_global_load_lds(
      (const __attribute__((address_space(1))) void*)g,
      (__attribute__((address_space(3))) void*)l, 16, 0, 0);
}

__device__ __forceinline__ unsigned pk2(float a, float b) {
  fp16x2n t = __builtin_amdgcn_cvt_pkrtz(a, b);
  return __builtin_bit_cast(unsigned, t);
}

// -------------------------- fused prep -------------------------------------
__global__ __launch_bounds__(256) void prep(const float* __restrict__ x,
                                            const float* __restrict__ wqkv,
                                            const float* __restrict__ wproj,
                                            _Float16* __restrict__ Xb,
                                            _Float16* __restrict__ Wqt,
                                            _Float16* __restrict__ Wpt) {
  __shared__ float t[64][65];
  const int id = blockIdx.x, tid = threadIdx.x;
  if (id < 4096) {
    int i = (id * 256 + tid) * 4;
    float4 v = *(const float4*)(x + i);
    f16x4 h;
    h[0] = (_Float16)v.x; h[1] = (_Float16)v.y;
    h[2] = (_Float16)v.z; h[3] = (_Float16)v.w;
    *(f16x4*)(Xb + i) = h;
    return;
  }
  const float* in; _Float16* out; int N, bx, by;
  if (id < 4864) { int tt = id - 4096; in = wqkv; out = Wqt; N = 3072; bx = tt % 48; by = tt / 48; }
  else           { int tt = id - 4864; in = wproj; out = Wpt; N = 1024; bx = tt & 15; by = tt >> 4; }
  const int n0 = bx * 64, k0 = by * 64;
  {
    int j = tid & 63;
#pragma unroll
    for (int p = 0; p < 16; p++) {
      int i = p * 4 + (tid >> 6);
      t[i][j] = in[(size_t)(k0 + i) * N + n0 + j];
    }
  }
  __syncthreads();
  {
    int i = tid & 63;
#pragma unroll
    for (int p = 0; p < 16; p++) {
      int j = p * 4 + (tid >> 6);
      out[(size_t)(n0 + j) * 1024 + k0 + i] = (_Float16)t[i][j];
    }
  }
}

// -------------------------- GEMM BK=64 (R6/R8 structure) -------------------
// C = A[M][K] @ Bt[N][K]^T, BMxBN tiles, 256 thr = 4 waves (2x2).
// LDS rows 128B, 8x16B chunks XOR-swizzled: slot = chunk ^ (row&7).
// EPI==0: Q/K planes scalar b16 (Q prescaled); V section -> Vt packed b64.
// EPI==1: fp32 out + bias.
template <int BM, int BN, int EPI>
__global__ __launch_bounds__(256) void gemm16(const _Float16* __restrict__ A,
                                              const _Float16* __restrict__ Bt,
                                              const int K,
                                              _Float16* __restrict__ oh,
                                              _Float16* __restrict__ vt,
                                              float* __restrict__ of,
                                              const float* __restrict__ bias,
                                              const int Nout) {
  constexpr int RF = BM / 32, CF = BN / 32;
  constexpr int SLABS = (BM + BN) / 8;
  __shared__ __align__(16) char smem[(BM + BN) * 128];
  char* As = smem;
  char* Bs = smem + BM * 128;
  const int tid = threadIdx.x, wave = tid >> 6, lane = tid & 63;
  const int il = lane & 15, ih = lane >> 4;
  const int bm = blockIdx.y * BM, bn = blockIdx.x * BN;
  const int wm = wave >> 1, wn = wave & 1;
  const int rs = lane >> 3, cp = lane & 7;

  f32x4 acc[RF][CF] = {};

  for (int k0 = 0; k0 < K; k0 += 64) {
    __syncthreads();
#pragma unroll
    for (int s0 = 0; s0 < SLABS / 4; s0++) {
      int s = wave + s0 * 4;
      int row = s * 8 + rs;
      int c = cp ^ (row & 7);
      if (row < BM)
        gload16(A + (size_t)(bm + row) * K + k0 + c * 8, As + s * 1024);
      else
        gload16(Bt + (size_t)(bn + row - BM) * K + k0 + c * 8, smem + s * 1024);
    }
    __syncthreads();
#pragma unroll
    for (int ks = 0; ks < 2; ks++) {
      f16x8 af[RF], bf[CF];
#pragma unroll
      for (int rf = 0; rf < RF; rf++) {
        int R = wm * (BM / 2) + rf * 16 + il;
        af[rf] = *(const f16x8*)(As + R * 128 + (((ks * 4 + ih) ^ (R & 7)) * 16));
      }
#pragma unroll
      for (int cf = 0; cf < CF; cf++) {
        int C = wn * (BN / 2) + cf * 16 + il;
        bf[cf] = *(const f16x8*)(Bs + C * 128 + (((ks * 4 + ih) ^ (C & 7)) * 16));
      }
#pragma unroll
      for (int rf = 0; rf < RF; rf++)
#pragma unroll
        for (int cf = 0; cf < CF; cf++)
          acc[rf][cf] = MFMA16(af[rf], bf[cf], acc[rf][cf]);
    }
  }

#pragma unroll
  for (int rf = 0; rf < RF; rf++)
#pragma unroll
    for (int cf = 0; cf < CF; cf++) {
      int row0 = bm + wm * (BM / 2) + rf * 16 + ih * 4;
      int col = bn + wn * (BN / 2) + cf * 16 + il;
      if (EPI == 0) {
        int sec = col >> 10, cc = col & 1023;
        if (sec == 2) {
          // V -> Vt [b*16+h][dh][2048]: 4 consecutive n (=row) at fixed dh
          int b = row0 >> 11, n = row0 & 2047;
          int bh = b * 16 + (cc >> 6), dh = cc & 63;
          union { f16x4 h; uint2 u; } pk;
#pragma unroll
          for (int r = 0; r < 4; r++) pk.h[r] = (_Float16)acc[rf][cf][r];
          *(uint2*)(vt + (size_t)bh * 131072 + (size_t)dh * 2048 + n) = pk.u;
        } else {
#pragma unroll
          for (int r = 0; r < 4; r++) {
            int row = row0 + r;
            float v = acc[rf][cf][r];
            if (sec == 0) v *= 0.18033688f;  // fold 0.125*log2(e) into Q
            size_t plane = (size_t)(sec * 32 + (row >> 11) * 16 + (cc >> 6));
            oh[plane * 131072 + (size_t)(row & 2047) * 64 + (cc & 63)] = (_Float16)v;
          }
        }
      } else {
#pragma unroll
        for (int r = 0; r < 4; r++)
          of[(size_t)(row0 + r) * Nout + col] = acc[rf][cf][r] + bias[col];
      }
    }
}

// -------------------------- banded flash attention v3 (R6, unchanged) ------
__global__ __launch_bounds__(512) void attn(const _Float16* __restrict__ QKV,
                                            const _Float16* __restrict__ VT,
                                            _Float16* __restrict__ O2) {
  __shared__ __align__(16) char smem[51200];
  const int tid = threadIdx.x, wave = tid >> 6, lane = tid & 63;
  const int qw = wave >> 1, sh = wave & 1;
  const int cl = lane & 31, hl = lane >> 5;
  const int rs = lane >> 3, cp = lane & 7;
  const int q0 = blockIdx.x * 128, bh = blockIdx.y;
  const _Float16* Qg = QKV + (size_t)bh * 131072;
  const _Float16* Kg = QKV + 4194304 + (size_t)bh * 131072;
  const _Float16* Vg = VT + (size_t)bh * 131072;
  const int t0 = (q0 >= 256) ? q0 - 256 : 0;
  const int t1 = (q0 + 384 <= 2048) ? q0 + 384 : 2048;
  const int niter = (t1 - t0) >> 6;

#pragma unroll
  for (int q = 0; q < 2; q++) {
    int s = 2 * wave + q;
    int row = s * 8 + rs;
    int c = cp ^ (row & 7);
    gload16(Qg + (size_t)(q0 + row) * 64 + c * 8, smem + s * 1024);
  }
  {
    char* B0 = smem + 18432;
    int row = wave * 8 + rs;
    int c = cp ^ (row & 7);
    gload16(Kg + (size_t)(t0 + row) * 64 + c * 8, B0 + wave * 1024);
    gload16(Vg + (size_t)row * 2048 + t0 + c * 8, B0 + 8192 + wave * 1024);
  }
  __syncthreads();

  f16x8 bq[4];
  {
    int row = 32 * qw + cl;
#pragma unroll
    for (int ks = 0; ks < 4; ks++)
      bq[ks] = *(const f16x8*)(smem + row * 128 + (((ks * 2 + hl) ^ (row & 7)) * 16));
  }
  __syncthreads();  // Q reads done before P overwrites staging region

  char* Pw = smem + wave * 2304;  // 32 rows x 72B
  f32x16 oacc[2] = {};
  float l_acc = 0.f;
  const int a0 = q0 + 32 * qw;

  for (int i = 0; i < niter; i++) {
    const int kt = t0 + i * 64;
    char* Bc = smem + 18432 + (i & 1) * 16384;
    if (i + 1 < niter) {
      char* Bn = smem + 18432 + ((i + 1) & 1) * 16384;
      int row = wave * 8 + rs;
      int c = cp ^ (row & 7);
      gload16(Kg + (size_t)(kt + 64 + row) * 64 + c * 8, Bn + wave * 1024);
      gload16(Vg + (size_t)row * 2048 + (kt + 64) + c * 8, Bn + 8192 + wave * 1024);
    }
    const int d0 = a0 - (kt + 32 * sh);
    if (d0 < 288 && d0 > -288) {
      char* Ksm = Bc;
      char* Vsm = Bc + 8192;
      f32x16 st = {};
      {
        const int krow = 32 * sh + cl;
#pragma unroll
        for (int ks = 0; ks < 4; ks++) {
          f16x8 ak = *(const f16x8*)(Ksm + krow * 128 + (((ks * 2 + hl) ^ (krow & 7)) * 16));
          st = MFMA32(ak, bq[ks], st);
        }
      }
#pragma unroll
      for (int g = 0; g < 4; g++) {
        float v[4];
#pragma unroll
        for (int i2 = 0; i2 < 4; i2++) {
          float e = __builtin_amdgcn_exp2f(st[4 * g + i2]);
          int kl = 8 * g + 4 * hl + i2;
          if (d0 == 256) e = (cl <= kl) ? e : 0.f;
          else if (d0 == -256) e = (cl >= kl) ? e : 0.f;
          l_acc += e;
          v[i2] = e;
        }
        uint2 w2 = {pk2(v[0], v[1]), pk2(v[2], v[3])};
        *(uint2*)(Pw + cl * 72 + 16 * g + 8 * hl) = w2;
      }
#pragma unroll
      for (int ks2 = 0; ks2 < 2; ks2++) {
        union { uint2 u2[2]; f16x8 h; } bp;
        bp.u2[0] = *(const uint2*)(Pw + cl * 72 + 32 * ks2 + 16 * hl);
        bp.u2[1] = *(const uint2*)(Pw + cl * 72 + 32 * ks2 + 16 * hl + 8);
#pragma unroll
        for (int db = 0; db < 2; db++) {
          int vrow = 32 * db + cl;
          f16x8 av = *(const f16x8*)(Vsm + vrow * 128 +
                                     (((4 * sh + 2 * ks2 + hl) ^ (vrow & 7)) * 16));
          oacc[db] = MFMA32(av, bp.h, oacc[db]);
        }
      }
    }
    __syncthreads();
  }

  const float lp = l_acc + __shfl_xor(l_acc, 32);
  char* Mq = smem + qw * 8448;
  if (sh == 1) {
#pragma unroll
    for (int db = 0; db < 2; db++)
#pragma unroll
      for (int g = 0; g < 4; g++) {
        int dh0 = 32 * db + 8 * g + 4 * hl;
        f32x2 a = {oacc[db][4 * g + 0], oacc[db][4 * g + 1]};
        f32x2 b = {oacc[db][4 * g + 2], oacc[db][4 * g + 3]};
        *(f32x2*)(Mq + cl * 264 + dh0 * 4) = a;
        *(f32x2*)(Mq + cl * 264 + dh0 * 4 + 8) = b;
      }
    if (hl == 0) *(float*)(smem + 34816 + (qw * 32 + cl) * 4) = lp;
  }
  __syncthreads();
  if (sh == 0) {
    float lo = *(const float*)(smem + 34816 + (qw * 32 + cl) * 4);
    float inv = 1.0f / (lp + lo);
    const int b = bh >> 4, h = bh & 15;
    _Float16* dst = O2 + (size_t)(b * 2048 + a0 + cl) * 1024 + h * 64;
#pragma unroll
    for (int db = 0; db < 2; db++)
#pragma unroll
      for (int g = 0; g < 4; g++) {
        int dh0 = 32 * db + 8 * g + 4 * hl;
        f32x2 a = *(const f32x2*)(Mq + cl * 264 + dh0 * 4);
        f32x2 b2 = *(const f32x2*)(Mq + cl * 264 + dh0 * 4 + 8);
        uint2 pkd = {pk2((oacc[db][4 * g + 0] + a[0]) * inv,
                         (oacc[db][4 * g + 1] + a[1]) * inv),
                     pk2((oacc[db][4 * g + 2] + b2[0]) * inv,
                         (oacc[db][4 * g + 3] + b2[1]) * inv)};
        *(uint2*)(dst + dh0) = pkd;
      }
  }
}

// -------------------------- host launch ------------------------------------

extern "C" void kernel_launch(void* const* d_in, const int* in_sizes, int n_in,
                              void* d_out, int out_size, void* d_ws, size_t ws_size,
                              hipStream_t stream) {
  const float* x = (const float*)d_in[0];
  const float* wqkv = (const float*)d_in[1];
  const float* wproj = (const float*)d_in[2];
  const float* bproj = (const float*)d_in[3];
  float* out = (float*)d_out;
  char* ws = (char*)d_ws;

  _Float16* Xb  = (_Float16*)(ws);                       // 8 MB [4096][1024]
  _Float16* Wqt = (_Float16*)(ws + (size_t)(8  << 20));  // 6 MB [3072][1024]
  _Float16* Wpt = (_Float16*)(ws + (size_t)(14 << 20));  // 2 MB [1024][1024]
  _Float16* QKV = (_Float16*)(ws + (size_t)(16 << 20));  // 16 MB Q,K planes
  _Float16* Vt  = (_Float16*)(ws + (size_t)(40 << 20));  // 8 MB [32][64][2048]
  _Float16* O2  = (_Float16*)(ws);                       // aliases Xb

  prep<<<5120, 256, 0, stream>>>(x, wqkv, wproj, Xb, Wqt, Wpt);
  gemm16<128, 128, 0><<<dim3(24, 32), 256, 0, stream>>>(Xb, Wqt, 1024, QKV, Vt,
                                                        nullptr, nullptr, 0);
  attn<<<dim3(16, 32), 512, 0, stream>>>(QKV, Vt, O2);
  gemm16<128, 64, 1><<<dim3(16, 32), 256, 0, stream>>>(O2, Wpt, 1024, nullptr,
                                                       nullptr, out, bproj, 1024);
}